// Round 10
// baseline (212.380 us; speedup 1.0000x reference)
//
#include <hip/hip_runtime.h>

using i32x4 = __attribute__((ext_vector_type(4))) int;

#define DEVI static __device__ __forceinline__

DEVI void gload_lds16(const void* g, void* l) {
  __builtin_amdgcn_global_load_lds(
      (const __attribute__((address_space(1))) void*)g,
      (__attribute__((address_space(3))) void*)l, 16, 0, 0);
}

template <int N> DEVI void vmcnt_n() {
  asm volatile("s_waitcnt vmcnt(%0)" ::"n"(N) : "memory");
}
template <int N> DEVI void lgkm_n() {
  asm volatile("s_waitcnt lgkmcnt(%0)" ::"n"(N) : "memory");
}

#define FENCE() asm volatile("" ::: "memory")
#define BARX()                    \
  do {                            \
    FENCE();                      \
    __builtin_amdgcn_s_barrier(); \
    FENCE();                      \
  } while (0)
#define SCHB() __builtin_amdgcn_sched_barrier(0)
#define PRIO1() __builtin_amdgcn_s_setprio(1)
#define PRIO0() __builtin_amdgcn_s_setprio(0)

// ------- pack int32 weights -> int8 in MFMA B-fragment order -------
// layout: chunk i (16B) = frag-block b = i>>6, lane l = i&63;
//   b = cblk*KB + kblk  (KB = K/64), c = cblk*16 + (l&15),
//   k0 = kblk*64 + (l>>4)*16 ; bytes = W[c][k0..k0+15] cast to i8.
DEVI unsigned pk4(const int* s) {
  return (unsigned)(unsigned char)s[0] | ((unsigned)(unsigned char)s[1] << 8) |
         ((unsigned)(unsigned char)s[2] << 16) |
         ((unsigned)(unsigned char)s[3] << 24);
}

__global__ void __launch_bounds__(256) pack_wfrag_kernel(
    const int* __restrict__ w, signed char* __restrict__ o, int K, int nchunks) {
  const int KB = K >> 6;
  int stride = gridDim.x * blockDim.x;
  for (int i = blockIdx.x * blockDim.x + threadIdx.x; i < nchunks; i += stride) {
    const int b = i >> 6, l = i & 63;
    const int cblk = b / KB, kblk = b - cblk * KB;
    const int c = cblk * 16 + (l & 15);
    const int k0 = kblk * 64 + (l >> 4) * 16;
    const int* src = w + (size_t)c * K + k0;
    int4 v;
    v.x = (int)pk4(src);
    v.y = (int)pk4(src + 4);
    v.z = (int)pk4(src + 8);
    v.w = (int)pk4(src + 12);
    *reinterpret_cast<int4*>(o + (size_t)i * 16) = v;
  }
}

// ---------------- quantize fp32 x -> int8 (row-major) ----------------
__global__ void __launch_bounds__(256) quant_x_kernel(const float* __restrict__ x,
                                                      signed char* __restrict__ o,
                                                      const float* __restrict__ amax,
                                                      int n4) {
  const float s = 127.0f / amax[0];
  int stride = gridDim.x * blockDim.x;
  for (int i = blockIdx.x * blockDim.x + threadIdx.x; i < n4; i += stride) {
    float4 v = reinterpret_cast<const float4*>(x)[i];
    char4 c;
    float q;
    q = fminf(fmaxf(rintf(__fmul_rn(v.x, s)), -127.0f), 127.0f); c.x = (signed char)(int)q;
    q = fminf(fmaxf(rintf(__fmul_rn(v.y, s)), -127.0f), 127.0f); c.y = (signed char)(int)q;
    q = fminf(fmaxf(rintf(__fmul_rn(v.z, s)), -127.0f), 127.0f); c.z = (signed char)(int)q;
    q = fminf(fmaxf(rintf(__fmul_rn(v.w, s)), -127.0f), 127.0f); c.w = (signed char)(int)q;
    reinterpret_cast<char4*>(o)[i] = c;
  }
}

// ---- int8 GEMM: A in LDS (R9 path: dbuf swizzled, gload_lds, 1 barrier/
// ---- tile); B streamed global->reg from FRAGMENT-PACKED W (no LDS at all).
// A: [M,K] i8 row-major; Wp: fragment-packed (see pack_wfrag_kernel).
// 8 waves (2M x 4N), per-wave C = 128 x (BN/4). BM=256, BK=128 bytes.

#define STG(b, kt)                                                               \
  do {                                                                           \
    const int k0_ = (kt)*128 + scol;                                             \
    gload_lds16(Ab + (size_t)(srow) * K + k0_, &lds[b][tid * 16]);               \
    gload_lds16(Ab + (size_t)(64 + srow) * K + k0_, &lds[b][8192 + tid * 16]);   \
    gload_lds16(Ab + (size_t)(128 + srow) * K + k0_, &lds[b][16384 + tid * 16]); \
    gload_lds16(Ab + (size_t)(192 + srow) * K + k0_, &lds[b][24576 + tid * 16]); \
  } while (0)

#define AF_(b, m, h) \
  (*(const i32x4*)&lds[b][(wrl + (m)*16 + ro) * 128 + ((h) ? cS1 : cS0)])

#define RD_AF(dst, b, m0)            \
  do {                               \
    dst[0][0] = AF_(b, m0, 0);       \
    dst[0][1] = AF_(b, m0, 1);       \
    dst[1][0] = AF_(b, (m0) + 1, 0); \
    dst[1][1] = AF_(b, (m0) + 1, 1); \
  } while (0)

// B fragments from packed W: one coalesced 1KB load per (n,h); offset
// (n*KB + 2t + h) * 1024 from the wave's fragment-column base.
#define LD_BF(dst, t)                                                           \
  do {                                                                          \
    _Pragma("unroll") for (int n = 0; n < NN; ++n) {                            \
      dst[n][0] = *(const i32x4*)(Wpw + ((size_t)(n)*KB + 2 * (t)) * 1024);     \
      dst[n][1] = *(const i32x4*)(Wpw + ((size_t)(n)*KB + 2 * (t) + 1) * 1024); \
    }                                                                           \
  } while (0)

#define MFMA_P(mp, af, bfc)                                                                \
  do {                                                                                     \
    _Pragma("unroll") for (int n = 0; n < NN; ++n) {                                       \
      acc[2 * (mp)][n] = __builtin_amdgcn_mfma_i32_16x16x64_i8(af[0][0], bfc[n][0],        \
                                                               acc[2 * (mp)][n], 0, 0, 0); \
      acc[2 * (mp)][n] = __builtin_amdgcn_mfma_i32_16x16x64_i8(af[0][1], bfc[n][1],        \
                                                               acc[2 * (mp)][n], 0, 0, 0); \
      acc[2 * (mp) + 1][n] = __builtin_amdgcn_mfma_i32_16x16x64_i8(                        \
          af[1][0], bfc[n][0], acc[2 * (mp) + 1][n], 0, 0, 0);                             \
      acc[2 * (mp) + 1][n] = __builtin_amdgcn_mfma_i32_16x16x64_i8(                        \
          af[1][1], bfc[n][1], acc[2 * (mp) + 1][n], 0, 0, 0);                             \
    }                                                                                      \
  } while (0)

// lgkm ledger (ds_reads only; bf loads are vmcnt class):
//  front: afX(4)+afY(4)=8; lgkm(4) -> afX; then per cluster as R9.
//  vmcnt(0) at tile end retires STG + LD_BF with ~full-tile cover.
#define TILE_R10(b, t, bfC, bfN)                   \
  do {                                             \
    RD_AF(afX, b, 0);                              \
    RD_AF(afY, b, 2);                              \
    if ((t) + 1 < nt) {                            \
      STG(1 - (b), (t) + 1);                       \
      LD_BF(bfN, (t) + 1);                         \
    }                                              \
    lgkm_n<4>(); SCHB();                           \
    PRIO1(); MFMA_P(0, afX, bfC); PRIO0();         \
    RD_AF(afX, b, 4);                              \
    lgkm_n<4>(); SCHB();                           \
    PRIO1(); MFMA_P(1, afY, bfC); PRIO0();         \
    RD_AF(afY, b, 6);                              \
    lgkm_n<4>(); SCHB();                           \
    PRIO1(); MFMA_P(2, afX, bfC); PRIO0();         \
    lgkm_n<0>(); SCHB();                           \
    PRIO1(); MFMA_P(3, afY, bfC); PRIO0();         \
    vmcnt_n<0>();                                  \
  } while (0)

template <int BN, int OUT_I8>
__global__ __launch_bounds__(512, 2) void gemm_r10_kernel(
    const signed char* __restrict__ A, const signed char* __restrict__ Wp,
    const int* __restrict__ bias, void* __restrict__ out, int M, int N, int K,
    const float* __restrict__ p_ain, const float* __restrict__ p_aw,
    const float* __restrict__ p_ab, const float* __restrict__ p_anext) {
  static_assert(BN == 256 || BN == 128, "");
  constexpr int NN = BN / 64;
  __shared__ signed char lds[2][256 * 128];  // A only: 2 x 32 KiB

  const int tid = threadIdx.x;
  const int lane = tid & 63;
  const int wave = tid >> 6;
  const int wrl = (wave >> 2) * 128;      // wave row offset in 256
  const int wcl = (wave & 3) * (BN / 4);  // wave col offset in BN

  // bijective XCD-chunked swizzle (nwg multiple of 8)
  const int lin = blockIdx.y * gridDim.x + blockIdx.x;
  const int cpx = (gridDim.x * gridDim.y) >> 3;
  const int swz = (lin & 7) * cpx + (lin >> 3);
  const int tileM = (swz / gridDim.x) * 256;
  const int tileN = (swz % gridDim.x) * BN;

  const signed char* Ab = A + (size_t)tileM * K;

  const int srow = tid >> 3;                       // staging row 0..63
  const int scol = ((tid & 7) ^ (srow & 7)) * 16;  // inverse-swizzled src col

  const int ro = lane & 15;  // fragment row within 16
  const int kg = lane >> 4;  // 16B k-group 0..3
  const int cS0 = ((kg ^ (ro & 7)) << 4);        // swizzled slot, k-half 0
  const int cS1 = (((4 + kg) ^ (ro & 7)) << 4);  // swizzled slot, k-half 1

  const int KB = K >> 6;  // 64B k-blocks
  const signed char* Wpw =
      Wp + ((size_t)((tileN + wcl) >> 4) * KB) * 1024 + (size_t)lane * 16;

  const int nt = K >> 7;  // K-tiles of 128 bytes (even for all layers)

  i32x4 acc[8][NN] = {};
  i32x4 afX[2][2], afY[2][2], bf0[NN][2], bf1[NN][2];

  // prologue: stage A(0), load B(0) regs; exact drain; loop barrier publishes
  STG(0, 0);
  LD_BF(bf0, 0);
  vmcnt_n<0>();

  for (int t = 0; t < nt; t += 2) {
    BARX();
    TILE_R10(0, t, bf0, bf1);
    BARX();
    TILE_R10(1, t + 1, bf1, bf0);
  }

  // ---- epilogue: dequant + bias (+ relu + requant) ----
  const float s1 = __fmul_rn(p_aw[0], p_ain[0]) / 16129.0f;  // a_w*a_in/127^2
  const float s2 = p_ab[0] / 127.0f;                         // a_b/127
  float qs = 0.0f;
  if (OUT_I8) qs = 127.0f / p_anext[0];

#pragma unroll
  for (int m = 0; m < 8; ++m) {
#pragma unroll
    for (int n = 0; n < NN; ++n) {
      const int col = tileN + wcl + n * 16 + ro;
      const int row0 = tileM + wrl + m * 16 + kg * 4;
      const float bv = __fmul_rn((float)bias[col], s2);
#pragma unroll
      for (int i = 0; i < 4; ++i) {
        float y = __fadd_rn(__fmul_rn((float)acc[m][n][i], s1), bv);
        if (OUT_I8) {
          float rl = fmaxf(y, 0.0f);
          float q = fminf(rintf(__fmul_rn(rl, qs)), 127.0f);
          ((signed char*)out)[(size_t)(row0 + i) * N + col] = (signed char)(int)q;
        } else {
          ((float*)out)[(size_t)(row0 + i) * N + col] = y;
        }
      }
    }
  }
}

extern "C" void kernel_launch(void* const* d_in, const int* in_sizes, int n_in,
                              void* d_out, int out_size, void* d_ws, size_t ws_size,
                              hipStream_t stream) {
  const float* x = (const float*)d_in[0];
  const int* W0 = (const int*)d_in[1];
  const int* b0 = (const int*)d_in[2];
  const int* W2 = (const int*)d_in[3];
  const int* b2 = (const int*)d_in[4];
  const int* W4 = (const int*)d_in[5];
  const int* b4 = (const int*)d_in[6];
  const float* a0_in = (const float*)d_in[7];
  const float* a0_w = (const float*)d_in[8];
  const float* a0_b = (const float*)d_in[9];
  const float* a2_in = (const float*)d_in[10];
  const float* a2_w = (const float*)d_in[11];
  const float* a2_b = (const float*)d_in[12];
  const float* a4_in = (const float*)d_in[13];
  const float* a4_w = (const float*)d_in[14];
  const float* a4_b = (const float*)d_in[15];

  constexpr int Bb = 4096, DIN = 2048, H = 4096, DOUT = 2048;
  constexpr size_t MB = 1u << 20;

  char* ws = (char*)d_ws;
  signed char* xq0 = (signed char*)(ws);           //  8 MB  [0,8)
  signed char* xq2 = (signed char*)(ws);           // 16 MB  [0,16) (aliases xq0+W0q, dead then)
  signed char* W0q = (signed char*)(ws + 8 * MB);  //  8 MB  [8,16)
  signed char* W2q = (signed char*)(ws + 16 * MB); // 16 MB  [16,32)
  signed char* W4q = (signed char*)(ws + 32 * MB); //  8 MB  [32,40)
  signed char* xq1 = (signed char*)(ws + 40 * MB); // 16 MB  [40,56)

  pack_wfrag_kernel<<<2048, 256, 0, stream>>>(W0, W0q, DIN, H * DIN / 16);
  pack_wfrag_kernel<<<2048, 256, 0, stream>>>(W2, W2q, H, H * H / 16);
  pack_wfrag_kernel<<<2048, 256, 0, stream>>>(W4, W4q, H, DOUT * H / 16);
  quant_x_kernel<<<2048, 256, 0, stream>>>(x, xq0, a0_in, Bb * DIN / 4);

  gemm_r10_kernel<256, 1><<<dim3(H / 256, Bb / 256), 512, 0, stream>>>(
      xq0, W0q, b0, xq1, Bb, H, DIN, a0_in, a0_w, a0_b, a2_in);
  gemm_r10_kernel<256, 1><<<dim3(H / 256, Bb / 256), 512, 0, stream>>>(
      xq1, W2q, b2, xq2, Bb, H, H, a2_in, a2_w, a2_b, a4_in);
  gemm_r10_kernel<128, 0><<<dim3(DOUT / 128, Bb / 256), 512, 0, stream>>>(
      xq2, W4q, b4, d_out, Bb, DOUT, H, a4_in, a4_w, a4_b, a4_in);
}

// Round 11
// 183.046 us; speedup vs baseline: 1.1603x; 1.1603x over previous
//
#include <hip/hip_runtime.h>

using i32x4 = __attribute__((ext_vector_type(4))) int;

#define DEVI static __device__ __forceinline__

DEVI void gload_lds16(const void* g, void* l) {
  __builtin_amdgcn_global_load_lds(
      (const __attribute__((address_space(1))) void*)g,
      (__attribute__((address_space(3))) void*)l, 16, 0, 0);
}

template <int N> DEVI void vmcnt_n() {
  asm volatile("s_waitcnt vmcnt(%0)" ::"n"(N) : "memory");
}
template <int N> DEVI void lgkm_n() {
  asm volatile("s_waitcnt lgkmcnt(%0)" ::"n"(N) : "memory");
}

#define FENCE() asm volatile("" ::: "memory")
#define BARX()                    \
  do {                            \
    FENCE();                      \
    __builtin_amdgcn_s_barrier(); \
    FENCE();                      \
  } while (0)
#define SCHB() __builtin_amdgcn_sched_barrier(0)
#define PRIO1() __builtin_amdgcn_s_setprio(1)
#define PRIO0() __builtin_amdgcn_s_setprio(0)

// ---------------- pack int32 weights -> int8 ----------------
__global__ void __launch_bounds__(256) pack_w_kernel(const int* __restrict__ w,
                                                     signed char* __restrict__ o,
                                                     int n4) {
  int stride = gridDim.x * blockDim.x;
  for (int i = blockIdx.x * blockDim.x + threadIdx.x; i < n4; i += stride) {
    int4 v = reinterpret_cast<const int4*>(w)[i];
    char4 c;
    c.x = (signed char)v.x;
    c.y = (signed char)v.y;
    c.z = (signed char)v.z;
    c.w = (signed char)v.w;
    reinterpret_cast<char4*>(o)[i] = c;
  }
}

// ---------------- quantize fp32 x -> int8 ----------------
__global__ void __launch_bounds__(256) quant_x_kernel(const float* __restrict__ x,
                                                      signed char* __restrict__ o,
                                                      const float* __restrict__ amax,
                                                      int n4) {
  const float s = 127.0f / amax[0];
  int stride = gridDim.x * blockDim.x;
  for (int i = blockIdx.x * blockDim.x + threadIdx.x; i < n4; i += stride) {
    float4 v = reinterpret_cast<const float4*>(x)[i];
    char4 c;
    float q;
    q = fminf(fmaxf(rintf(__fmul_rn(v.x, s)), -127.0f), 127.0f); c.x = (signed char)(int)q;
    q = fminf(fmaxf(rintf(__fmul_rn(v.y, s)), -127.0f), 127.0f); c.y = (signed char)(int)q;
    q = fminf(fmaxf(rintf(__fmul_rn(v.z, s)), -127.0f), 127.0f); c.z = (signed char)(int)q;
    q = fminf(fmaxf(rintf(__fmul_rn(v.w, s)), -127.0f), 127.0f); c.w = (signed char)(int)q;
    reinterpret_cast<char4*>(o)[i] = c;
  }
}

// ---- int8 GEMM: BMx128 tile, BK=64, 8 waves (2M x 4N), 2 blocks/CU ----
// A: [M,K] i8 row-major; W: [N,K] i8 row-major.
// R9 protocol: dbuf swizzled LDS both operands via gload_lds; ONE barrier
// per tile; own-wave lgkm ledger; single vmcnt(0) drain at tile end.
// BK=64 swizzle: row r slot s holds global col16 = s ^ ((r>>1)&3); read
// slot = kg ^ ((ro>>1)&3) -> 2 lanes/bank-set per 16-lane phase (free).

#define STG(b, kt)                                                          \
  do {                                                                      \
    const int k0_ = (kt)*64 + scol;                                         \
    _Pragma("unroll") for (int j = 0; j < BM / 128; ++j)                    \
        gload_lds16(Ab + (size_t)(j * 128 + srow) * K + k0_,                \
                    &lds[b][j * 8192 + tid * 16]);                          \
    gload_lds16(Wb + (size_t)srow * K + k0_, &lds[b][ABYTES + tid * 16]);   \
  } while (0)

#define AF_(b, m) (*(const i32x4*)&lds[b][(wrl + (m)*16 + ro) * 64 + cS])
#define BF_(b, n) (*(const i32x4*)&lds[b][ABYTES + (wcl + (n)*16 + ro) * 64 + cS])

#define RD_A2(dst, b, m0)    \
  do {                       \
    dst[0] = AF_(b, m0);     \
    dst[1] = AF_(b, (m0)+1); \
  } while (0)

#define RD_BF(b)        \
  do {                  \
    bf[0] = BF_(b, 0);  \
    bf[1] = BF_(b, 1);  \
  } while (0)

#define CL(mp, af)                                                            \
  do {                                                                        \
    _Pragma("unroll") for (int n = 0; n < 2; ++n) {                           \
      acc[2 * (mp)][n] = __builtin_amdgcn_mfma_i32_16x16x64_i8(               \
          af[0], bf[n], acc[2 * (mp)][n], 0, 0, 0);                           \
      acc[2 * (mp) + 1][n] = __builtin_amdgcn_mfma_i32_16x16x64_i8(           \
          af[1], bf[n], acc[2 * (mp) + 1][n], 0, 0, 0);                       \
    }                                                                         \
  } while (0)

// ledger (ds_reads, in-order, own-wave):
//  front: bf(2) + afX(2) + afY(2); lgkm(2) retires bf+afX -> CL0(afX)
//  MF=8: RD afX'; lgkm(2) retires afY -> CL1(afY); RD afY'; lgkm(2)
//        retires afX' -> CL2; lgkm(0) -> CL3.
#define TILE(b, t)                             \
  do {                                         \
    RD_BF(b);                                  \
    RD_A2(afX, b, 0);                          \
    RD_A2(afY, b, 2);                          \
    if ((t) + 1 < nt) STG(1 - (b), (t) + 1);   \
    lgkm_n<2>(); SCHB();                       \
    PRIO1(); CL(0, afX); PRIO0();              \
    if constexpr (MF == 8) {                   \
      RD_A2(afX, b, 4);                        \
      lgkm_n<2>(); SCHB();                     \
      PRIO1(); CL(1, afY); PRIO0();            \
      RD_A2(afY, b, 6);                        \
      lgkm_n<2>(); SCHB();                     \
      PRIO1(); CL(2, afX); PRIO0();            \
      lgkm_n<0>(); SCHB();                     \
      PRIO1(); CL(3, afY); PRIO0();            \
    } else {                                   \
      lgkm_n<0>(); SCHB();                     \
      PRIO1(); CL(1, afY); PRIO0();            \
    }                                          \
    vmcnt_n<0>();                              \
  } while (0)

template <int BM, int OUT_I8>
__global__ __launch_bounds__(512, 4) void gemm_r11_kernel(
    const signed char* __restrict__ A, const signed char* __restrict__ W,
    const int* __restrict__ bias, void* __restrict__ out, int M, int N, int K,
    const float* __restrict__ p_ain, const float* __restrict__ p_aw,
    const float* __restrict__ p_ab, const float* __restrict__ p_anext) {
  static_assert(BM == 256 || BM == 128, "");
  constexpr int MF = BM / 32;        // m-frags per wave (8 or 4)
  constexpr int ABYTES = BM * 64;    // A region per buffer
  __shared__ signed char lds[2][ABYTES + 128 * 64];

  const int tid = threadIdx.x;
  const int lane = tid & 63;
  const int wave = tid >> 6;
  const int wrl = (wave >> 2) * (BM / 2);  // wave row offset
  const int wcl = (wave & 3) * 32;         // wave col offset in 128

  // bijective XCD-chunked swizzle (nwg = 512, multiple of 8)
  const int lin = blockIdx.y * gridDim.x + blockIdx.x;
  const int cpx = (gridDim.x * gridDim.y) >> 3;
  const int swz = (lin & 7) * cpx + (lin >> 3);
  const int tileM = (swz / gridDim.x) * BM;
  const int tileN = (swz % gridDim.x) * 128;

  const signed char* Ab = A + (size_t)tileM * K;
  const signed char* Wb = W + (size_t)tileN * K;

  const int srow = tid >> 2;                        // staging row 0..127
  const int scol = ((tid & 3) ^ ((tid >> 3) & 3)) * 16;  // inverse-swz src col

  const int ro = lane & 15;  // fragment row within 16
  const int kg = lane >> 4;  // 16B k-group 0..3
  const int cS = ((kg ^ ((ro >> 1) & 3)) << 4);  // swizzled slot byte

  const int nt = K >> 6;  // K-tiles of 64 bytes (even for all layers)

  i32x4 acc[MF][2] = {};
  i32x4 afX[2], afY[2], bf[2];

  // prologue: stage tile 0, retire own DMAs; loop-entry barrier publishes
  STG(0, 0);
  vmcnt_n<0>();

  for (int t = 0; t < nt; t += 2) {
    BARX();
    TILE(0, t);
    BARX();
    TILE(1, t + 1);
  }

  // ---- epilogue: dequant + bias (+ relu + requant) ----
  const float s1 = __fmul_rn(p_aw[0], p_ain[0]) / 16129.0f;  // a_w*a_in/127^2
  const float s2 = p_ab[0] / 127.0f;                         // a_b/127
  float qs = 0.0f;
  if (OUT_I8) qs = 127.0f / p_anext[0];

#pragma unroll
  for (int m = 0; m < MF; ++m) {
#pragma unroll
    for (int n = 0; n < 2; ++n) {
      const int col = tileN + wcl + n * 16 + ro;
      const int row0 = tileM + wrl + m * 16 + kg * 4;
      const float bv = __fmul_rn((float)bias[col], s2);
#pragma unroll
      for (int i = 0; i < 4; ++i) {
        float y = __fadd_rn(__fmul_rn((float)acc[m][n][i], s1), bv);
        if (OUT_I8) {
          float rl = fmaxf(y, 0.0f);
          float q = fminf(rintf(__fmul_rn(rl, qs)), 127.0f);
          ((signed char*)out)[(size_t)(row0 + i) * N + col] = (signed char)(int)q;
        } else {
          ((float*)out)[(size_t)(row0 + i) * N + col] = y;
        }
      }
    }
  }
}

extern "C" void kernel_launch(void* const* d_in, const int* in_sizes, int n_in,
                              void* d_out, int out_size, void* d_ws, size_t ws_size,
                              hipStream_t stream) {
  const float* x = (const float*)d_in[0];
  const int* W0 = (const int*)d_in[1];
  const int* b0 = (const int*)d_in[2];
  const int* W2 = (const int*)d_in[3];
  const int* b2 = (const int*)d_in[4];
  const int* W4 = (const int*)d_in[5];
  const int* b4 = (const int*)d_in[6];
  const float* a0_in = (const float*)d_in[7];
  const float* a0_w = (const float*)d_in[8];
  const float* a0_b = (const float*)d_in[9];
  const float* a2_in = (const float*)d_in[10];
  const float* a2_w = (const float*)d_in[11];
  const float* a2_b = (const float*)d_in[12];
  const float* a4_in = (const float*)d_in[13];
  const float* a4_w = (const float*)d_in[14];
  const float* a4_b = (const float*)d_in[15];

  constexpr int Bb = 4096, DIN = 2048, H = 4096, DOUT = 2048;
  constexpr size_t MB = 1u << 20;

  char* ws = (char*)d_ws;
  signed char* xq0 = (signed char*)(ws);           //  8 MB  [0,8)
  signed char* xq2 = (signed char*)(ws);           // 16 MB  [0,16) (aliases xq0+W0q, dead then)
  signed char* W0q = (signed char*)(ws + 8 * MB);  //  8 MB  [8,16)
  signed char* W2q = (signed char*)(ws + 16 * MB); // 16 MB  [16,32)
  signed char* W4q = (signed char*)(ws + 32 * MB); //  8 MB  [32,40)
  signed char* xq1 = (signed char*)(ws + 40 * MB); // 16 MB  [40,56)

  pack_w_kernel<<<2048, 256, 0, stream>>>(W0, W0q, H * DIN / 4);
  pack_w_kernel<<<2048, 256, 0, stream>>>(W2, W2q, H * H / 4);
  pack_w_kernel<<<2048, 256, 0, stream>>>(W4, W4q, DOUT * H / 4);
  quant_x_kernel<<<2048, 256, 0, stream>>>(x, xq0, a0_in, Bb * DIN / 4);

  gemm_r11_kernel<256, 1><<<dim3(H / 128, Bb / 256), 512, 0, stream>>>(
      xq0, W0q, b0, xq1, Bb, H, DIN, a0_in, a0_w, a0_b, a2_in);
  gemm_r11_kernel<256, 1><<<dim3(H / 128, Bb / 256), 512, 0, stream>>>(
      xq1, W2q, b2, xq2, Bb, H, H, a2_in, a2_w, a2_b, a4_in);
  gemm_r11_kernel<128, 0><<<dim3(DOUT / 128, Bb / 128), 512, 0, stream>>>(
      xq2, W4q, b4, d_out, Bb, DOUT, H, a4_in, a4_w, a4_b, a4_in);
}